// Round 11
// baseline (441.250 us; speedup 1.0000x reference)
//
#include <hip/hip_runtime.h>

#define NN 10000
#define NE 640000
#define CH 128
#define NH 8
#define HD 16
#define BD 32
#define NEG 0.01f

#define PROJ_BLOCKS (NN / 16)            // 625
#define HIST_BLOCKS ((NE + 255) / 256)   // 2500

__device__ __forceinline__ float rdlane(float v, int idx) {
    return __int_as_float(__builtin_amdgcn_readlane(__float_as_int(v), idx));
}

// bf16 round-to-nearest-even pack/unpack (K path only: logit-side error
// ~1e-3 at the output, proven R10 absmax 0.00195 vs 0.00836 threshold).
__device__ __forceinline__ unsigned bf16rne(float f) {
    unsigned b = __float_as_uint(f);
    b += 0x7fffu + ((b >> 16) & 1u);
    return b >> 16;
}
__device__ __forceinline__ float bf16up(unsigned u) {
    return __uint_as_float(u << 16);
}

// DPP butterfly sums: pure VALU, no DS pipe.
template <int CTRL>
__device__ __forceinline__ float dpp_add(float x) {
    int v = __builtin_amdgcn_update_dpp(0, __float_as_int(x), CTRL, 0xF, 0xF, true);
    return x + __int_as_float(v);
}
// Sum over each 8-lane group (one head = 16 channels = 8 lanes in the
// pair-per-lane layout). After xor1+xor2 all quads are uniform, so
// row_half_mirror (xor 7) completes the 8-wide butterfly.
__device__ __forceinline__ float sum8(float x) {
    x = dpp_add<0xB1>(x);   // quad_perm xor1
    x = dpp_add<0x4E>(x);   // quad_perm xor2
    x = dpp_add<0x141>(x);  // row_half_mirror (== xor4 after stages 1,2)
    return x;
}

// ---------------- proj + hist fused (independent work, concurrent blocks) ----
// Lane l owns channel pair (2l, 2l+1): float2 W loads (half the load count),
// float2/packed-uint outputs matching the fused kernel's layout.
__device__ void proj_body(
    int blk, const float* __restrict__ senders, const float* __restrict__ receivers,
    const float2* __restrict__ WQ2, const float2* __restrict__ WK2,
    const float2* __restrict__ WV2,
    float2* __restrict__ Qn2, unsigned* __restrict__ KBu,
    float2* __restrict__ Vn2)
{
    int wave = threadIdx.x >> 6, l = threadIdx.x & 63;
    int n0 = (blk * 4 + wave) * 4;
    float2 r[4], s[4];
#pragma unroll
    for (int i = 0; i < 4; ++i) {
        r[i] = ((const float2*)(receivers + (size_t)(n0 + i) * CH))[l];
        s[i] = ((const float2*)(senders   + (size_t)(n0 + i) * CH))[l];
    }
    float2 q[4], k[4], v[4];
#pragma unroll
    for (int i = 0; i < 4; ++i) {
        q[i] = make_float2(0.f, 0.f);
        k[i] = make_float2(0.f, 0.f);
        v[i] = make_float2(0.f, 0.f);
    }
    for (int kk2 = 0; kk2 < 64; ++kk2) {
        // W rows 2*kk2 and 2*kk2+1, channel pair (2l,2l+1)
        float2 wq0 = WQ2[(2 * kk2) * 64 + l], wq1 = WQ2[(2 * kk2 + 1) * 64 + l];
        float2 wk0 = WK2[(2 * kk2) * 64 + l], wk1 = WK2[(2 * kk2 + 1) * 64 + l];
        float2 wv0 = WV2[(2 * kk2) * 64 + l], wv1 = WV2[(2 * kk2 + 1) * 64 + l];
#pragma unroll
        for (int i = 0; i < 4; ++i) {
            float rv0 = rdlane(r[i].x, kk2), rv1 = rdlane(r[i].y, kk2);
            float sv0 = rdlane(s[i].x, kk2), sv1 = rdlane(s[i].y, kk2);
            q[i].x = fmaf(rv0, wq0.x, q[i].x); q[i].x = fmaf(rv1, wq1.x, q[i].x);
            q[i].y = fmaf(rv0, wq0.y, q[i].y); q[i].y = fmaf(rv1, wq1.y, q[i].y);
            k[i].x = fmaf(sv0, wk0.x, k[i].x); k[i].x = fmaf(sv1, wk1.x, k[i].x);
            k[i].y = fmaf(sv0, wk0.y, k[i].y); k[i].y = fmaf(sv1, wk1.y, k[i].y);
            v[i].x = fmaf(sv0, wv0.x, v[i].x); v[i].x = fmaf(sv1, wv1.x, v[i].x);
            v[i].y = fmaf(sv0, wv0.y, v[i].y); v[i].y = fmaf(sv1, wv1.y, v[i].y);
        }
    }
#pragma unroll
    for (int i = 0; i < 4; ++i) {
        size_t o = (size_t)(n0 + i) * 64 + l;
        Qn2[o] = q[i];
        KBu[o] = bf16rne(k[i].x) | (bf16rne(k[i].y) << 16);
        Vn2[o] = v[i];
    }
}

__global__ __launch_bounds__(256) void proj_hist_kernel(
    const float* __restrict__ senders, const float* __restrict__ receivers,
    const float2* __restrict__ WQ2, const float2* __restrict__ WK2,
    const float2* __restrict__ WV2,
    float2* __restrict__ Qn2, unsigned* __restrict__ KBu,
    float2* __restrict__ Vn2,
    const int* __restrict__ eidx, int* __restrict__ counts,
    int* __restrict__ rank)
{
    if (blockIdx.x < PROJ_BLOCKS) {
        proj_body(blockIdx.x, senders, receivers, WQ2, WK2, WV2, Qn2, KBu, Vn2);
    } else {
        int e = (blockIdx.x - PROJ_BLOCKS) * 256 + threadIdx.x;
        if (e < NE) rank[e] = atomicAdd(&counts[eidx[NE + e]], 1);
    }
}

// ---------------- prefix scan (single block, LDS-coalesced) ------------------
// R10's version did strided global accesses (thread t <-> counts[t*10..]):
// ~120k uncoalesced line touches from one CU. Stage through LDS instead.
__global__ __launch_bounds__(1024) void scan_kernel(
    const int* __restrict__ counts, int* __restrict__ starts)
{
    __shared__ int ls[NN];     // 40 KB
    __shared__ int s[1024];
    int tid = threadIdx.x;
    for (int i = tid; i < NN; i += 1024) ls[i] = counts[i];
    __syncthreads();
    const int CHUNK = 10;      // 1024*10 >= NN
    int base = tid * CHUNK;
    int local = 0;
#pragma unroll
    for (int j = 0; j < CHUNK; ++j) {
        int i = base + j;
        if (i < NN) local += ls[i];
    }
    s[tid] = local;
    __syncthreads();
    for (int off = 1; off < 1024; off <<= 1) {
        int t = (tid >= off) ? s[tid - off] : 0;
        __syncthreads();
        s[tid] += t;
        __syncthreads();
    }
    int run = s[tid] - local;  // exclusive prefix of this chunk
#pragma unroll
    for (int j = 0; j < CHUNK; ++j) {
        int i = base + j;
        if (i < NN) { int c = ls[i]; ls[i] = run; run += c; }
    }
    __syncthreads();
    for (int i = tid; i < NN; i += 1024) starts[i] = ls[i];
    if (tid == 1023) starts[NN] = s[1023];
}

// ---------------- scatter: one int2 {edge, src} per slot ---------------------
__global__ void scatter_kernel(const int* __restrict__ eidx,
                               const int* __restrict__ rank,
                               const int* __restrict__ starts,
                               int2* __restrict__ es)
{
    int e = blockIdx.x * blockDim.x + threadIdx.x;
    if (e < NE) {
        int p = starts[eidx[NE + e]] + rank[e];
        es[p] = make_int2(e, eidx[e]);
    }
}

// ---------------- fused per-node edge loop (R6/R10 skeleton) -----------------
// One WAVE per node; lane l owns channel pair (2l, 2l+1). Per edge:
// 1 uint K load + 1 float2 V load (was 4 loads), 32 float2 WE loads from
// L1-resident 16 KB WE (t-loop invariant, hoistable at the compiler's
// discretion - residency made irrelevant, not fought for), 3 DPP + 1 exp
// per edge (was 8 + 2). eattr rows via wave-uniform s_load as in R6/R10.
__global__ __launch_bounds__(256) void fused_kernel(
    const int2* __restrict__ es, const int* __restrict__ starts,
    const float* __restrict__ eattr, const float2* __restrict__ WE2,
    const float2* __restrict__ att2, const float2* __restrict__ Qn2,
    const unsigned* __restrict__ KBu, const float2* __restrict__ Vn2,
    float2* __restrict__ out2)
{
    int wave = threadIdx.x >> 6, l = threadIdx.x & 63;
    int n = blockIdx.x * 4 + wave;            // 2500 blocks * 4 waves = NN
    int start = starts[n], end = starts[n + 1];

    float2 a = att2[l];
    float2 q = Qn2[(size_t)n * 64 + l];
    float2 acc = make_float2(0.f, 0.f);
    float sume = 0.f;

    for (int base = start; base < end; base += 8) {
        int m = end - base;                   // >=1
        int idx = base + (l & 7);
        if (idx >= end) idx = end - 1;
        int2 esv = es[idx];
#pragma unroll 8
        for (int t = 0; t < 8; ++t) {
            if (t >= m) break;                // wave-uniform
            int e   = __builtin_amdgcn_readlane(esv.x, t);
            int src = __builtin_amdgcn_readlane(esv.y, t);
            const float* __restrict__ row = eattr + (size_t)e * BD;
            unsigned kb = KBu[(size_t)src * 64 + l];
            float2 vv = Vn2[(size_t)src * 64 + l];
            float2 ec = make_float2(0.f, 0.f);
#pragma unroll
            for (int k = 0; k < BD; ++k) {
                float rv = row[k];            // uniform -> s_load
                float2 w = WE2[k * 64 + l];   // L1-hot, t-invariant
                ec.x = fmaf(rv, w.x, ec.x);
                ec.y = fmaf(rv, w.y, ec.y);
            }
            float h0 = q.x + bf16up(kb & 0xffffu) + ec.x;
            float h1 = q.y + bf16up(kb >> 16) + ec.y;
            h0 = h0 > 0.f ? h0 : NEG * h0;
            h1 = h1 > 0.f ? h1 : NEG * h1;
            float p = fmaf(a.y, h1, a.x * h0);
            p = sum8(p);                      // head logit in all 8 lanes
            float ex = __expf(p);
            sume += ex;
            acc.x = fmaf(ex, vv.x, acc.x);
            acc.y = fmaf(ex, vv.y, acc.y);
        }
    }
    float inv = (end > start) ? 1.f / sume : 0.f;
    out2[(size_t)n * 64 + l] = make_float2(acc.x * inv, acc.y * inv);
}

extern "C" void kernel_launch(void* const* d_in, const int* in_sizes, int n_in,
                              void* d_out, int out_size, void* d_ws, size_t ws_size,
                              hipStream_t stream)
{
    const float* senders   = (const float*)d_in[0];
    const float* receivers = (const float*)d_in[1];
    const int*   eidx      = (const int*)d_in[2];
    const float* eattr     = (const float*)d_in[3];
    const float2* WQ2 = (const float2*)d_in[4];
    const float2* WK2 = (const float2*)d_in[5];
    const float2* WV2 = (const float2*)d_in[6];
    const float2* WE2 = (const float2*)d_in[7];
    const float2* att2 = (const float2*)d_in[8];
    float2* out2 = (float2*)d_out;

    char* ws = (char*)d_ws;
    size_t off = 0;
    auto alloc = [&](size_t bytes) -> void* {
        void* p = ws + off;
        off += (bytes + 255) & ~(size_t)255;
        return p;
    };
    // Total ~20.6 MB (< 38.5 MB proven safe in R1; R2's 43.7 MB failed)
    float2*   Qn2    = (float2*)alloc((size_t)NN * 64 * 8);
    unsigned* KBu    = (unsigned*)alloc((size_t)NN * 64 * 4);
    float2*   Vn2    = (float2*)alloc((size_t)NN * 64 * 8);
    int*      counts = (int*)alloc((size_t)NN * 4);
    int*      starts = (int*)alloc((size_t)(NN + 1) * 4);
    int*      rank   = (int*)alloc((size_t)NE * 4);
    int2*     es     = (int2*)alloc((size_t)NE * 8);

    hipMemsetAsync(counts, 0, (size_t)NN * 4, stream);
    proj_hist_kernel<<<PROJ_BLOCKS + HIST_BLOCKS, 256, 0, stream>>>(
        senders, receivers, WQ2, WK2, WV2, Qn2, KBu, Vn2, eidx, counts, rank);
    scan_kernel<<<1, 1024, 0, stream>>>(counts, starts);
    scatter_kernel<<<HIST_BLOCKS, 256, 0, stream>>>(eidx, rank, starts, es);
    fused_kernel<<<NN / 4, 256, 0, stream>>>(es, starts, eattr, WE2, att2, Qn2, KBu, Vn2, out2);
}

// Round 12
// 335.782 us; speedup vs baseline: 1.3141x; 1.3141x over previous
//
#include <hip/hip_runtime.h>

#define NN 10000
#define NE 640000
#define CH 128
#define NH 8
#define HD 16
#define BD 32
#define NEG 0.01f
#define SLOTS 160   // per-node edge-slot stride; deg ~ Poisson(64), P(>=160) ~ 1e-25

#define PROJ_BLOCKS (NN / 16)            // 625
#define HIST_BLOCKS ((NE + 255) / 256)   // 2500

__device__ __forceinline__ float rdlane(float v, int idx) {
    return __int_as_float(__builtin_amdgcn_readlane(__float_as_int(v), idx));
}

// bf16 round-to-nearest-even pack/unpack (K path only: logit-side error,
// proven R10 absmax 0.00195 vs 0.00836 threshold).
__device__ __forceinline__ unsigned short bf16rne(float f) {
    unsigned b = __float_as_uint(f);
    b += 0x7fffu + ((b >> 16) & 1u);
    return (unsigned short)(b >> 16);
}
__device__ __forceinline__ float bf16up(unsigned short u) {
    return __uint_as_float((unsigned)u << 16);
}

// DPP butterfly sum over each 16-lane row (one head = 16 channels): pure VALU.
template <int CTRL>
__device__ __forceinline__ float dpp_add(float x) {
    int v = __builtin_amdgcn_update_dpp(0, __float_as_int(x), CTRL, 0xF, 0xF, true);
    return x + __int_as_float(v);
}
__device__ __forceinline__ float sum16(float x) {
    x = dpp_add<0xB1>(x);   // quad_perm xor1
    x = dpp_add<0x4E>(x);   // quad_perm xor2
    x = dpp_add<0x141>(x);  // row_half_mirror
    x = dpp_add<0x140>(x);  // row_mirror
    return x;
}

// ---------------- proj + hist fused (independent work, concurrent blocks) ----
// R10 proj_body verbatim.
__device__ void proj_body(
    int blk, const float* __restrict__ senders, const float* __restrict__ receivers,
    const float* __restrict__ WQ, const float* __restrict__ WK,
    const float* __restrict__ WV,
    float* __restrict__ Qn, unsigned short* __restrict__ KB,
    float* __restrict__ Vn)
{
    int wave = threadIdx.x >> 6, l = threadIdx.x & 63;
    int n0 = (blk * 4 + wave) * 4;
    float r0[4], r1[4], s0[4], s1[4];
#pragma unroll
    for (int i = 0; i < 4; ++i) {
        r0[i] = receivers[(size_t)(n0 + i) * CH + l];
        r1[i] = receivers[(size_t)(n0 + i) * CH + 64 + l];
        s0[i] = senders[(size_t)(n0 + i) * CH + l];
        s1[i] = senders[(size_t)(n0 + i) * CH + 64 + l];
    }
    float q0[4] = {0,0,0,0}, q1[4] = {0,0,0,0};
    float k0[4] = {0,0,0,0}, k1[4] = {0,0,0,0};
    float v0[4] = {0,0,0,0}, v1[4] = {0,0,0,0};
    for (int ln = 0; ln < 64; ++ln) {
        float wq0 = WQ[ln * CH + l], wq1 = WQ[ln * CH + 64 + l];
        float wk0 = WK[ln * CH + l], wk1 = WK[ln * CH + 64 + l];
        float wv0 = WV[ln * CH + l], wv1 = WV[ln * CH + 64 + l];
#pragma unroll
        for (int i = 0; i < 4; ++i) {
            float rv = rdlane(r0[i], ln);
            float sv = rdlane(s0[i], ln);
            q0[i] = fmaf(rv, wq0, q0[i]);  q1[i] = fmaf(rv, wq1, q1[i]);
            k0[i] = fmaf(sv, wk0, k0[i]);  k1[i] = fmaf(sv, wk1, k1[i]);
            v0[i] = fmaf(sv, wv0, v0[i]);  v1[i] = fmaf(sv, wv1, v1[i]);
        }
    }
    for (int ln = 0; ln < 64; ++ln) {
        int kk = 64 + ln;
        float wq0 = WQ[kk * CH + l], wq1 = WQ[kk * CH + 64 + l];
        float wk0 = WK[kk * CH + l], wk1 = WK[kk * CH + 64 + l];
        float wv0 = WV[kk * CH + l], wv1 = WV[kk * CH + 64 + l];
#pragma unroll
        for (int i = 0; i < 4; ++i) {
            float rv = rdlane(r1[i], ln);
            float sv = rdlane(s1[i], ln);
            q0[i] = fmaf(rv, wq0, q0[i]);  q1[i] = fmaf(rv, wq1, q1[i]);
            k0[i] = fmaf(sv, wk0, k0[i]);  k1[i] = fmaf(sv, wk1, k1[i]);
            v0[i] = fmaf(sv, wv0, v0[i]);  v1[i] = fmaf(sv, wv1, v1[i]);
        }
    }
#pragma unroll
    for (int i = 0; i < 4; ++i) {
        size_t o = (size_t)(n0 + i) * CH;
        Qn[o + l] = q0[i];
        Qn[o + 64 + l] = q1[i];
        KB[o + l] = bf16rne(k0[i]);
        KB[o + 64 + l] = bf16rne(k1[i]);
        Vn[o + l] = v0[i];
        Vn[o + 64 + l] = v1[i];
    }
}

__global__ __launch_bounds__(256) void proj_hist_kernel(
    const float* __restrict__ senders, const float* __restrict__ receivers,
    const float* __restrict__ WQ, const float* __restrict__ WK,
    const float* __restrict__ WV,
    float* __restrict__ Qn, unsigned short* __restrict__ KB,
    float* __restrict__ Vn,
    const int* __restrict__ eidx, int* __restrict__ counts,
    int* __restrict__ rank)
{
    if (blockIdx.x < PROJ_BLOCKS) {
        proj_body(blockIdx.x, senders, receivers, WQ, WK, WV, Qn, KB, Vn);
    } else {
        int e = (blockIdx.x - PROJ_BLOCKS) * 256 + threadIdx.x;
        if (e < NE) rank[e] = atomicAdd(&counts[eidx[NE + e]], 1);
    }
}

// ---------------- scatter into fixed-stride slots (NO SCAN NEEDED) -----------
__global__ void scatter_kernel(const int* __restrict__ eidx,
                               const int* __restrict__ rank,
                               int2* __restrict__ es)
{
    int e = blockIdx.x * blockDim.x + threadIdx.x;
    if (e < NE) {
        int p = eidx[NE + e] * SLOTS + rank[e];
        es[p] = make_int2(e, eidx[e]);
    }
}

// ---------------- fused per-node edge loop (R10 structure verbatim) ----------
// One WAVE per node, lane l owns channels l and l+64. 8-edge tiles; eattr
// rows via wave-uniform s_load; K gathered as bf16, V f32. Slot base is
// n*SLOTS, edge count from counts[n]. R8/R9/R11 lessons: do not reshape
// this loop.
__global__ __launch_bounds__(256, 4) void fused_kernel(
    const int2* __restrict__ es, const int* __restrict__ counts,
    const float* __restrict__ eattr, const float* __restrict__ WE,
    const float* __restrict__ att, const float* __restrict__ Qn,
    const unsigned short* __restrict__ KB, const float* __restrict__ Vn,
    float* __restrict__ out)
{
    int wave = threadIdx.x >> 6, l = threadIdx.x & 63;
    int n = blockIdx.x * 4 + wave;            // 2500 blocks * 4 waves = NN
    int start = n * SLOTS;
    int end = start + counts[n];

    float rWE[2 * BD];
#pragma unroll
    for (int k = 0; k < BD; ++k) {
        rWE[k]      = WE[k * CH + l];
        rWE[BD + k] = WE[k * CH + 64 + l];
    }
#pragma unroll
    for (int k = 0; k < 2 * BD; ++k) asm volatile("" : "+v"(rWE[k]));

    float a0 = att[l], a1 = att[64 + l];
    float q0 = Qn[(size_t)n * CH + l], q1 = Qn[(size_t)n * CH + 64 + l];
    float acc0 = 0.f, acc1 = 0.f, sum0 = 0.f, sum1 = 0.f;

    for (int base = start; base < end; base += 8) {
        int m = end - base;                   // >=1
        int idx = base + (l & 7);
        if (idx >= end) idx = end - 1;
        int2 esv = es[idx];
#pragma unroll 8
        for (int t = 0; t < 8; ++t) {
            if (t >= m) break;                // wave-uniform
            int e   = __builtin_amdgcn_readlane(esv.x, t);
            int src = __builtin_amdgcn_readlane(esv.y, t);
            const float* __restrict__ row = eattr + (size_t)e * BD;
            size_t so = (size_t)src * CH;
            float kb0 = bf16up(KB[so + l]);
            float kb1 = bf16up(KB[so + 64 + l]);
            float vv0 = Vn[so + l];
            float vv1 = Vn[so + 64 + l];
            float ec0 = 0.f, ec1 = 0.f;
#pragma unroll
            for (int k = 0; k < BD; ++k) {
                float rv = row[k];            // uniform -> s_load
                ec0 = fmaf(rv, rWE[k],      ec0);
                ec1 = fmaf(rv, rWE[BD + k], ec1);
            }
            float h0 = q0 + kb0 + ec0; h0 = h0 > 0.f ? h0 : NEG * h0;
            float h1 = q1 + kb1 + ec1; h1 = h1 > 0.f ? h1 : NEG * h1;
            float t0 = sum16(a0 * h0);
            float t1 = sum16(a1 * h1);
            float e0 = __expf(t0), e1 = __expf(t1);
            sum0 += e0; acc0 = fmaf(e0, vv0, acc0);
            sum1 += e1; acc1 = fmaf(e1, vv1, acc1);
        }
    }
    out[(size_t)n * CH + l]      = (end > start) ? acc0 / sum0 : 0.f;
    out[(size_t)n * CH + 64 + l] = (end > start) ? acc1 / sum1 : 0.f;
}

extern "C" void kernel_launch(void* const* d_in, const int* in_sizes, int n_in,
                              void* d_out, int out_size, void* d_ws, size_t ws_size,
                              hipStream_t stream)
{
    const float* senders   = (const float*)d_in[0];
    const float* receivers = (const float*)d_in[1];
    const int*   eidx      = (const int*)d_in[2];
    const float* eattr     = (const float*)d_in[3];
    const float* WQ  = (const float*)d_in[4];
    const float* WK  = (const float*)d_in[5];
    const float* WV  = (const float*)d_in[6];
    const float* WE  = (const float*)d_in[7];
    const float* att = (const float*)d_in[8];
    float* out = (float*)d_out;

    char* ws = (char*)d_ws;
    size_t off = 0;
    auto alloc = [&](size_t bytes) -> void* {
        void* p = ws + off;
        off += (bytes + 255) & ~(size_t)255;
        return p;
    };
    // Total ~28.4 MB (< 38.5 MB proven safe in R1; R2's 43.7 MB failed)
    float*          Qn     = (float*)alloc((size_t)NN * CH * 4);
    unsigned short* KB     = (unsigned short*)alloc((size_t)NN * CH * 2);
    float*          Vn     = (float*)alloc((size_t)NN * CH * 4);
    int*            counts = (int*)alloc((size_t)NN * 4);
    int*            rank   = (int*)alloc((size_t)NE * 4);
    int2*           es     = (int2*)alloc((size_t)NN * SLOTS * 8);

    hipMemsetAsync(counts, 0, (size_t)NN * 4, stream);
    proj_hist_kernel<<<PROJ_BLOCKS + HIST_BLOCKS, 256, 0, stream>>>(
        senders, receivers, WQ, WK, WV, Qn, KB, Vn, eidx, counts, rank);
    scatter_kernel<<<HIST_BLOCKS, 256, 0, stream>>>(eidx, rank, es);
    fused_kernel<<<NN / 4, 256, 0, stream>>>(es, counts, eattr, WE, att, Qn, KB, Vn, out);
}

// Round 13
// 327.440 us; speedup vs baseline: 1.3476x; 1.0255x over previous
//
#include <hip/hip_runtime.h>

#define NN 10000
#define NE 640000
#define CH 128
#define NH 8
#define HD 16
#define BD 32
#define NEG 0.01f
#define SLOTS 160   // per-node edge-slot stride; deg ~ Poisson(64), P(>=160) ~ 1e-25

#define PROJ_BLOCKS (NN / 16)            // 625
#define HIST_BLOCKS ((NE + 255) / 256)   // 2500

__device__ __forceinline__ float rdlane(float v, int idx) {
    return __int_as_float(__builtin_amdgcn_readlane(__float_as_int(v), idx));
}

// bf16 round-to-nearest-even pack/unpack (K path only: logit-side error,
// proven R10-R12 absmax 0.00195 vs 0.00836 threshold).
__device__ __forceinline__ unsigned short bf16rne(float f) {
    unsigned b = __float_as_uint(f);
    b += 0x7fffu + ((b >> 16) & 1u);
    return (unsigned short)(b >> 16);
}
__device__ __forceinline__ float bf16up(unsigned short u) {
    return __uint_as_float((unsigned)u << 16);
}

// DPP butterfly sum over each 16-lane row (one head = 16 channels): pure VALU.
template <int CTRL>
__device__ __forceinline__ float dpp_add(float x) {
    int v = __builtin_amdgcn_update_dpp(0, __float_as_int(x), CTRL, 0xF, 0xF, true);
    return x + __int_as_float(v);
}
__device__ __forceinline__ float sum16(float x) {
    x = dpp_add<0xB1>(x);   // quad_perm xor1
    x = dpp_add<0x4E>(x);   // quad_perm xor2
    x = dpp_add<0x141>(x);  // row_half_mirror
    x = dpp_add<0x140>(x);  // row_mirror
    return x;
}

// ---------------- proj + hist+scatter fused (independent, concurrent) --------
// R10 proj_body verbatim.
__device__ void proj_body(
    int blk, const float* __restrict__ senders, const float* __restrict__ receivers,
    const float* __restrict__ WQ, const float* __restrict__ WK,
    const float* __restrict__ WV,
    float* __restrict__ Qn, unsigned short* __restrict__ KB,
    float* __restrict__ Vn)
{
    int wave = threadIdx.x >> 6, l = threadIdx.x & 63;
    int n0 = (blk * 4 + wave) * 4;
    float r0[4], r1[4], s0[4], s1[4];
#pragma unroll
    for (int i = 0; i < 4; ++i) {
        r0[i] = receivers[(size_t)(n0 + i) * CH + l];
        r1[i] = receivers[(size_t)(n0 + i) * CH + 64 + l];
        s0[i] = senders[(size_t)(n0 + i) * CH + l];
        s1[i] = senders[(size_t)(n0 + i) * CH + 64 + l];
    }
    float q0[4] = {0,0,0,0}, q1[4] = {0,0,0,0};
    float k0[4] = {0,0,0,0}, k1[4] = {0,0,0,0};
    float v0[4] = {0,0,0,0}, v1[4] = {0,0,0,0};
    for (int ln = 0; ln < 64; ++ln) {
        float wq0 = WQ[ln * CH + l], wq1 = WQ[ln * CH + 64 + l];
        float wk0 = WK[ln * CH + l], wk1 = WK[ln * CH + 64 + l];
        float wv0 = WV[ln * CH + l], wv1 = WV[ln * CH + 64 + l];
#pragma unroll
        for (int i = 0; i < 4; ++i) {
            float rv = rdlane(r0[i], ln);
            float sv = rdlane(s0[i], ln);
            q0[i] = fmaf(rv, wq0, q0[i]);  q1[i] = fmaf(rv, wq1, q1[i]);
            k0[i] = fmaf(sv, wk0, k0[i]);  k1[i] = fmaf(sv, wk1, k1[i]);
            v0[i] = fmaf(sv, wv0, v0[i]);  v1[i] = fmaf(sv, wv1, v1[i]);
        }
    }
    for (int ln = 0; ln < 64; ++ln) {
        int kk = 64 + ln;
        float wq0 = WQ[kk * CH + l], wq1 = WQ[kk * CH + 64 + l];
        float wk0 = WK[kk * CH + l], wk1 = WK[kk * CH + 64 + l];
        float wv0 = WV[kk * CH + l], wv1 = WV[kk * CH + 64 + l];
#pragma unroll
        for (int i = 0; i < 4; ++i) {
            float rv = rdlane(r1[i], ln);
            float sv = rdlane(s1[i], ln);
            q0[i] = fmaf(rv, wq0, q0[i]);  q1[i] = fmaf(rv, wq1, q1[i]);
            k0[i] = fmaf(sv, wk0, k0[i]);  k1[i] = fmaf(sv, wk1, k1[i]);
            v0[i] = fmaf(sv, wv0, v0[i]);  v1[i] = fmaf(sv, wv1, v1[i]);
        }
    }
#pragma unroll
    for (int i = 0; i < 4; ++i) {
        size_t o = (size_t)(n0 + i) * CH;
        Qn[o + l] = q0[i];
        Qn[o + 64 + l] = q1[i];
        KB[o + l] = bf16rne(k0[i]);
        KB[o + 64 + l] = bf16rne(k1[i]);
        Vn[o + l] = v0[i];
        Vn[o + 64 + l] = v1[i];
    }
}

__global__ __launch_bounds__(256) void proj_hist_kernel(
    const float* __restrict__ senders, const float* __restrict__ receivers,
    const float* __restrict__ WQ, const float* __restrict__ WK,
    const float* __restrict__ WV,
    float* __restrict__ Qn, unsigned short* __restrict__ KB,
    float* __restrict__ Vn,
    const int* __restrict__ eidx, int* __restrict__ counts,
    int2* __restrict__ es)
{
    if (blockIdx.x < PROJ_BLOCKS) {
        proj_body(blockIdx.x, senders, receivers, WQ, WK, WV, Qn, KB, Vn);
    } else {
        int e = (blockIdx.x - PROJ_BLOCKS) * 256 + threadIdx.x;
        if (e < NE) {
            int d = eidx[NE + e];
            int r = atomicAdd(&counts[d], 1);
            es[d * SLOTS + r] = make_int2(e, eidx[e]);  // scatter fused in
        }
    }
}

// ---------------- fused per-node edge loop (R10 structure verbatim) ----------
// One WAVE per node, lane l owns channels l and l+64. 8-edge tiles; eattr
// rows via wave-uniform s_load; K gathered as bf16, V f32. Slot base n*SLOTS,
// count from counts[n]. R8/R9/R11 lessons: do not reshape this loop.
__global__ __launch_bounds__(256, 4) void fused_kernel(
    const int2* __restrict__ es, const int* __restrict__ counts,
    const float* __restrict__ eattr, const float* __restrict__ WE,
    const float* __restrict__ att, const float* __restrict__ Qn,
    const unsigned short* __restrict__ KB, const float* __restrict__ Vn,
    float* __restrict__ out)
{
    int wave = threadIdx.x >> 6, l = threadIdx.x & 63;
    int n = blockIdx.x * 4 + wave;            // 2500 blocks * 4 waves = NN
    int start = n * SLOTS;
    int end = start + counts[n];

    float rWE[2 * BD];
#pragma unroll
    for (int k = 0; k < BD; ++k) {
        rWE[k]      = WE[k * CH + l];
        rWE[BD + k] = WE[k * CH + 64 + l];
    }
#pragma unroll
    for (int k = 0; k < 2 * BD; ++k) asm volatile("" : "+v"(rWE[k]));

    float a0 = att[l], a1 = att[64 + l];
    float q0 = Qn[(size_t)n * CH + l], q1 = Qn[(size_t)n * CH + 64 + l];
    float acc0 = 0.f, acc1 = 0.f, sum0 = 0.f, sum1 = 0.f;

    for (int base = start; base < end; base += 8) {
        int m = end - base;                   // >=1
        int idx = base + (l & 7);
        if (idx >= end) idx = end - 1;
        int2 esv = es[idx];
#pragma unroll 8
        for (int t = 0; t < 8; ++t) {
            if (t >= m) break;                // wave-uniform
            int e   = __builtin_amdgcn_readlane(esv.x, t);
            int src = __builtin_amdgcn_readlane(esv.y, t);
            const float* __restrict__ row = eattr + (size_t)e * BD;
            size_t so = (size_t)src * CH;
            float kb0 = bf16up(KB[so + l]);
            float kb1 = bf16up(KB[so + 64 + l]);
            float vv0 = Vn[so + l];
            float vv1 = Vn[so + 64 + l];
            float ec0 = 0.f, ec1 = 0.f;
#pragma unroll
            for (int k = 0; k < BD; ++k) {
                float rv = row[k];            // uniform -> s_load
                ec0 = fmaf(rv, rWE[k],      ec0);
                ec1 = fmaf(rv, rWE[BD + k], ec1);
            }
            float h0 = q0 + kb0 + ec0; h0 = h0 > 0.f ? h0 : NEG * h0;
            float h1 = q1 + kb1 + ec1; h1 = h1 > 0.f ? h1 : NEG * h1;
            float t0 = sum16(a0 * h0);
            float t1 = sum16(a1 * h1);
            float e0 = __expf(t0), e1 = __expf(t1);
            sum0 += e0; acc0 = fmaf(e0, vv0, acc0);
            sum1 += e1; acc1 = fmaf(e1, vv1, acc1);
        }
    }
    out[(size_t)n * CH + l]      = (end > start) ? acc0 / sum0 : 0.f;
    out[(size_t)n * CH + 64 + l] = (end > start) ? acc1 / sum1 : 0.f;
}

extern "C" void kernel_launch(void* const* d_in, const int* in_sizes, int n_in,
                              void* d_out, int out_size, void* d_ws, size_t ws_size,
                              hipStream_t stream)
{
    const float* senders   = (const float*)d_in[0];
    const float* receivers = (const float*)d_in[1];
    const int*   eidx      = (const int*)d_in[2];
    const float* eattr     = (const float*)d_in[3];
    const float* WQ  = (const float*)d_in[4];
    const float* WK  = (const float*)d_in[5];
    const float* WV  = (const float*)d_in[6];
    const float* WE  = (const float*)d_in[7];
    const float* att = (const float*)d_in[8];
    float* out = (float*)d_out;

    char* ws = (char*)d_ws;
    size_t off = 0;
    auto alloc = [&](size_t bytes) -> void* {
        void* p = ws + off;
        off += (bytes + 255) & ~(size_t)255;
        return p;
    };
    // Total ~25.9 MB (< 38.5 MB proven safe in R1; R2's 43.7 MB failed)
    float*          Qn     = (float*)alloc((size_t)NN * CH * 4);
    unsigned short* KB     = (unsigned short*)alloc((size_t)NN * CH * 2);
    float*          Vn     = (float*)alloc((size_t)NN * CH * 4);
    int*            counts = (int*)alloc((size_t)NN * 4);
    int2*           es     = (int2*)alloc((size_t)NN * SLOTS * 8);

    hipMemsetAsync(counts, 0, (size_t)NN * 4, stream);
    proj_hist_kernel<<<PROJ_BLOCKS + HIST_BLOCKS, 256, 0, stream>>>(
        senders, receivers, WQ, WK, WV, Qn, KB, Vn, eidx, counts, es);
    fused_kernel<<<NN / 4, 256, 0, stream>>>(es, counts, eattr, WE, att, Qn, KB, Vn, out);
}

// Round 14
// 325.370 us; speedup vs baseline: 1.3561x; 1.0064x over previous
//
#include <hip/hip_runtime.h>

#define NN 10000
#define NE 640000
#define CH 128
#define NH 8
#define HD 16
#define BD 32
#define NEG 0.01f
#define SLOTS 160   // per-node edge-slot stride; deg ~ Poisson(64), P(>=160) ~ 1e-25

#define PROJ_BLOCKS (NN / 16)            // 625
#define HIST_BLOCKS ((NE + 255) / 256)   // 2500

__device__ __forceinline__ float rdlane(float v, int idx) {
    return __int_as_float(__builtin_amdgcn_readlane(__float_as_int(v), idx));
}

// bf16 round-to-nearest-even pack; K and V both bf16 now (K: logit-side,
// proven R10-R13; V: output-side, error ~0.002 softmax-averaged, budget ok).
__device__ __forceinline__ unsigned bf16rne(float f) {
    unsigned b = __float_as_uint(f);
    b += 0x7fffu + ((b >> 16) & 1u);
    return b >> 16;
}

// DPP butterfly sum over each 16-lane row (one head = 16 channels): pure VALU.
template <int CTRL>
__device__ __forceinline__ float dpp_add(float x) {
    int v = __builtin_amdgcn_update_dpp(0, __float_as_int(x), CTRL, 0xF, 0xF, true);
    return x + __int_as_float(v);
}
__device__ __forceinline__ float sum16(float x) {
    x = dpp_add<0xB1>(x);   // quad_perm xor1
    x = dpp_add<0x4E>(x);   // quad_perm xor2
    x = dpp_add<0x141>(x);  // row_half_mirror
    x = dpp_add<0x140>(x);  // row_mirror
    return x;
}

// ---------------- proj + hist+scatter fused (independent, concurrent) --------
// R10 proj_body, except K,V are packed bf16 pairs into one uint per channel:
// KVP[node*CH + c] = {K bf16 (low), V bf16 (high)} -> 512 B/node row.
__device__ void proj_body(
    int blk, const float* __restrict__ senders, const float* __restrict__ receivers,
    const float* __restrict__ WQ, const float* __restrict__ WK,
    const float* __restrict__ WV,
    float* __restrict__ Qn, unsigned* __restrict__ KVP)
{
    int wave = threadIdx.x >> 6, l = threadIdx.x & 63;
    int n0 = (blk * 4 + wave) * 4;
    float r0[4], r1[4], s0[4], s1[4];
#pragma unroll
    for (int i = 0; i < 4; ++i) {
        r0[i] = receivers[(size_t)(n0 + i) * CH + l];
        r1[i] = receivers[(size_t)(n0 + i) * CH + 64 + l];
        s0[i] = senders[(size_t)(n0 + i) * CH + l];
        s1[i] = senders[(size_t)(n0 + i) * CH + 64 + l];
    }
    float q0[4] = {0,0,0,0}, q1[4] = {0,0,0,0};
    float k0[4] = {0,0,0,0}, k1[4] = {0,0,0,0};
    float v0[4] = {0,0,0,0}, v1[4] = {0,0,0,0};
    for (int ln = 0; ln < 64; ++ln) {
        float wq0 = WQ[ln * CH + l], wq1 = WQ[ln * CH + 64 + l];
        float wk0 = WK[ln * CH + l], wk1 = WK[ln * CH + 64 + l];
        float wv0 = WV[ln * CH + l], wv1 = WV[ln * CH + 64 + l];
#pragma unroll
        for (int i = 0; i < 4; ++i) {
            float rv = rdlane(r0[i], ln);
            float sv = rdlane(s0[i], ln);
            q0[i] = fmaf(rv, wq0, q0[i]);  q1[i] = fmaf(rv, wq1, q1[i]);
            k0[i] = fmaf(sv, wk0, k0[i]);  k1[i] = fmaf(sv, wk1, k1[i]);
            v0[i] = fmaf(sv, wv0, v0[i]);  v1[i] = fmaf(sv, wv1, v1[i]);
        }
    }
    for (int ln = 0; ln < 64; ++ln) {
        int kk = 64 + ln;
        float wq0 = WQ[kk * CH + l], wq1 = WQ[kk * CH + 64 + l];
        float wk0 = WK[kk * CH + l], wk1 = WK[kk * CH + 64 + l];
        float wv0 = WV[kk * CH + l], wv1 = WV[kk * CH + 64 + l];
#pragma unroll
        for (int i = 0; i < 4; ++i) {
            float rv = rdlane(r1[i], ln);
            float sv = rdlane(s1[i], ln);
            q0[i] = fmaf(rv, wq0, q0[i]);  q1[i] = fmaf(rv, wq1, q1[i]);
            k0[i] = fmaf(sv, wk0, k0[i]);  k1[i] = fmaf(sv, wk1, k1[i]);
            v0[i] = fmaf(sv, wv0, v0[i]);  v1[i] = fmaf(sv, wv1, v1[i]);
        }
    }
#pragma unroll
    for (int i = 0; i < 4; ++i) {
        size_t o = (size_t)(n0 + i) * CH;
        Qn[o + l] = q0[i];
        Qn[o + 64 + l] = q1[i];
        KVP[o + l]      = bf16rne(k0[i]) | (bf16rne(v0[i]) << 16);
        KVP[o + 64 + l] = bf16rne(k1[i]) | (bf16rne(v1[i]) << 16);
    }
}

__global__ __launch_bounds__(256) void proj_hist_kernel(
    const float* __restrict__ senders, const float* __restrict__ receivers,
    const float* __restrict__ WQ, const float* __restrict__ WK,
    const float* __restrict__ WV,
    float* __restrict__ Qn, unsigned* __restrict__ KVP,
    const int* __restrict__ eidx, int* __restrict__ counts,
    int2* __restrict__ es)
{
    if (blockIdx.x < PROJ_BLOCKS) {
        proj_body(blockIdx.x, senders, receivers, WQ, WK, WV, Qn, KVP);
    } else {
        int e = (blockIdx.x - PROJ_BLOCKS) * 256 + threadIdx.x;
        if (e < NE) {
            int d = eidx[NE + e];
            int r = atomicAdd(&counts[d], 1);
            es[d * SLOTS + r] = make_int2(e, eidx[e]);  // scatter fused in
        }
    }
}

// ---------------- fused per-node edge loop (R10 structure; KV packed) --------
// One WAVE per node, lane l owns channels l and l+64. 8-edge tiles; eattr
// rows via wave-uniform s_load. KV gather: ONE dword per (edge, lane, half)
// - 8 cache lines per edge (was 12), 2 loads (was 4). Unpack: k = pack<<16,
// v = pack & 0xffff0000 (1 VALU op each). Do not reshape this loop
// (R8/R9/R11 regressions).
__global__ __launch_bounds__(256, 4) void fused_kernel(
    const int2* __restrict__ es, const int* __restrict__ counts,
    const float* __restrict__ eattr, const float* __restrict__ WE,
    const float* __restrict__ att, const float* __restrict__ Qn,
    const unsigned* __restrict__ KVP, float* __restrict__ out)
{
    int wave = threadIdx.x >> 6, l = threadIdx.x & 63;
    int n = blockIdx.x * 4 + wave;            // 2500 blocks * 4 waves = NN
    int start = n * SLOTS;
    int end = start + counts[n];

    float rWE[2 * BD];
#pragma unroll
    for (int k = 0; k < BD; ++k) {
        rWE[k]      = WE[k * CH + l];
        rWE[BD + k] = WE[k * CH + 64 + l];
    }
#pragma unroll
    for (int k = 0; k < 2 * BD; ++k) asm volatile("" : "+v"(rWE[k]));

    float a0 = att[l], a1 = att[64 + l];
    float q0 = Qn[(size_t)n * CH + l], q1 = Qn[(size_t)n * CH + 64 + l];
    float acc0 = 0.f, acc1 = 0.f, sum0 = 0.f, sum1 = 0.f;

    for (int base = start; base < end; base += 8) {
        int m = end - base;                   // >=1
        int idx = base + (l & 7);
        if (idx >= end) idx = end - 1;
        int2 esv = es[idx];
#pragma unroll 8
        for (int t = 0; t < 8; ++t) {
            if (t >= m) break;                // wave-uniform
            int e   = __builtin_amdgcn_readlane(esv.x, t);
            int src = __builtin_amdgcn_readlane(esv.y, t);
            const float* __restrict__ row = eattr + (size_t)e * BD;
            size_t so = (size_t)src * CH;
            unsigned p0 = KVP[so + l];
            unsigned p1 = KVP[so + 64 + l];
            float kb0 = __uint_as_float(p0 << 16);
            float kb1 = __uint_as_float(p1 << 16);
            float vv0 = __uint_as_float(p0 & 0xffff0000u);
            float vv1 = __uint_as_float(p1 & 0xffff0000u);
            float ec0 = 0.f, ec1 = 0.f;
#pragma unroll
            for (int k = 0; k < BD; ++k) {
                float rv = row[k];            // uniform -> s_load
                ec0 = fmaf(rv, rWE[k],      ec0);
                ec1 = fmaf(rv, rWE[BD + k], ec1);
            }
            float h0 = q0 + kb0 + ec0; h0 = h0 > 0.f ? h0 : NEG * h0;
            float h1 = q1 + kb1 + ec1; h1 = h1 > 0.f ? h1 : NEG * h1;
            float t0 = sum16(a0 * h0);
            float t1 = sum16(a1 * h1);
            float e0 = __expf(t0), e1 = __expf(t1);
            sum0 += e0; acc0 = fmaf(e0, vv0, acc0);
            sum1 += e1; acc1 = fmaf(e1, vv1, acc1);
        }
    }
    out[(size_t)n * CH + l]      = (end > start) ? acc0 / sum0 : 0.f;
    out[(size_t)n * CH + 64 + l] = (end > start) ? acc1 / sum1 : 0.f;
}

extern "C" void kernel_launch(void* const* d_in, const int* in_sizes, int n_in,
                              void* d_out, int out_size, void* d_ws, size_t ws_size,
                              hipStream_t stream)
{
    const float* senders   = (const float*)d_in[0];
    const float* receivers = (const float*)d_in[1];
    const int*   eidx      = (const int*)d_in[2];
    const float* eattr     = (const float*)d_in[3];
    const float* WQ  = (const float*)d_in[4];
    const float* WK  = (const float*)d_in[5];
    const float* WV  = (const float*)d_in[6];
    const float* WE  = (const float*)d_in[7];
    const float* att = (const float*)d_in[8];
    float* out = (float*)d_out;

    char* ws = (char*)d_ws;
    size_t off = 0;
    auto alloc = [&](size_t bytes) -> void* {
        void* p = ws + off;
        off += (bytes + 255) & ~(size_t)255;
        return p;
    };
    // Total ~23.2 MB (< 38.5 MB proven safe in R1; R2's 43.7 MB failed)
    float*    Qn     = (float*)alloc((size_t)NN * CH * 4);
    unsigned* KVP    = (unsigned*)alloc((size_t)NN * CH * 4);
    int*      counts = (int*)alloc((size_t)NN * 4);
    int2*     es     = (int2*)alloc((size_t)NN * SLOTS * 8);

    hipMemsetAsync(counts, 0, (size_t)NN * 4, stream);
    proj_hist_kernel<<<PROJ_BLOCKS + HIST_BLOCKS, 256, 0, stream>>>(
        senders, receivers, WQ, WK, WV, Qn, KVP, eidx, counts, es);
    fused_kernel<<<NN / 4, 256, 0, stream>>>(es, counts, eattr, WE, att, Qn, KVP, out);
}